// Round 7
// baseline (347.507 us; speedup 1.0000x reference)
//
#include <hip/hip_runtime.h>
#include <math.h>

typedef __bf16 bf16x8 __attribute__((ext_vector_type(8)));
typedef float  f32x4  __attribute__((ext_vector_type(4)));
// may_alias views for the unioned LDS region (A-frags <-> per-wave zbuf)
typedef bf16x8 bf16x8_a __attribute__((may_alias));
typedef f32x4  f32x4_a  __attribute__((may_alias));
typedef float  f32_a    __attribute__((may_alias));

#define MSAMP 9       // samples per block; rows: row = s*9 + m, row 63 = pad

__device__ __forceinline__ float tanh_fast(float x) {
    // 1 - 2/(exp(2x)+1); v_exp_f32 + v_rcp_f32, ~1e-6 abs error, saturates to +-1
    const float e = __expf(2.0f * x);
    return 1.0f - 2.0f * __builtin_amdgcn_rcpf(e + 1.0f);
}

__device__ __forceinline__ void couple8(const float z[7][8], const float bvv[8],
                                        float stt[7][8]) {
    #pragma unroll
    for (int jj = 0; jj < 8; ++jj) {
        const float zH  = z[0][jj] + bvv[jj];
        const float zt0 = z[1][jj], zt1 = z[2][jj], zt2 = z[3][jj];
        const float zr0 = z[4][jj], zr1 = z[5][jj], zr2 = z[6][jj];
        const float h   = tanh_fast(zH);
        const float dd  = 1.0f - h*h;
        const float qq  = -2.0f * h * (zt0 + zt1 + zt2);
        stt[0][jj] = h;
        stt[1][jj] = dd * zt0; stt[2][jj] = dd * zt1; stt[3][jj] = dd * zt2;
        stt[4][jj] = dd * (zr0 + qq*zt0);
        stt[5][jj] = dd * (zr1 + qq*zt1);
        stt[6][jj] = dd * (zr2 + qq*zt2);
    }
}

__device__ __forceinline__ void writeA(bf16x8_a* AhiV, bf16x8_a* AloV,
                                       const float stt[7][8],
                                       int ktx, int lqx, int mx) {
    #pragma unroll
    for (int s = 0; s < 7; ++s) {
        const int row = s*9 + mx;
        const int vid = (ktx*4 + (row>>4))*64 + lqx*16 + (row & 15);
        bf16x8 vh, vl;
        #pragma unroll
        for (int jj = 0; jj < 8; ++jj) {
            vh[jj] = (__bf16)stt[s][jj];
            vl[jj] = (__bf16)(stt[s][jj] - (float)vh[jj]);
        }
        AhiV[vid] = vh;
        AloV[vid] = vl;
    }
}

// W swizzle (bf16 elems): off(l,kt,nt,split,lane,j) =
//   (((l*8+kt)*16+nt)*2+split)*512 + lane*8 + j      ; per-l stride 131072 elems
// One B-fragment (16x16x32): lane holds B[k=kt*32+(lane>>4)*8+j][n=nt*16+(lane&15)]
__global__ void prep_w(const float* __restrict__ W1, const float* __restrict__ W2,
                       const float* __restrict__ W3, __bf16* __restrict__ wsw) {
    const int tid = blockIdx.x * 256 + threadIdx.x;      // 3*8*16*64*8 = 196608
    if (tid >= 3 * 8 * 16 * 64 * 8) return;
    const int j    = tid & 7;
    const int lane = (tid >> 3) & 63;
    const int nt   = (tid >> 9) & 15;
    const int kt   = (tid >> 13) & 7;
    const int l    = tid >> 16;
    const float* W = (l == 0) ? W1 : (l == 1) ? W2 : W3;
    const int k = kt * 32 + (lane >> 4) * 8 + j;
    const int n = nt * 16 + (lane & 15);
    const float w = W[k * 256 + n];
    const __bf16 hi = (__bf16)w;
    const __bf16 lo = (__bf16)(w - (float)hi);
    const size_t base = ((size_t)((l * 8 + kt) * 16 + nt) * 2) * 512 + lane * 8 + j;
    wsw[base]       = hi;
    wsw[base + 512] = lo;
}

// zbuf mapping (wave-local, over the wave's own kt slices {2wv,2wv+1} hi+lo):
//   mask(row) = ((row>>2)&3)<<3 | ((row>>4)&1)<<2   (bits>=2 only: f32x4-safe)
//   word(row,cw) = wv*2048 + (row>>5)*8192 + (row&31)*64 + (cw ^ mask(row))
__global__ __launch_bounds__(256, 2)
void pinn_mfma(const float* __restrict__ X,
               const float* __restrict__ W0, const float* __restrict__ b0,
               const float* __restrict__ b1, const float* __restrict__ b2,
               const float* __restrict__ b3,
               const float* __restrict__ W4, const float* __restrict__ b4,
               const float* __restrict__ lb, const float* __restrict__ ub,
               const __bf16* __restrict__ wsw,
               float* __restrict__ out, int N)
{
    __shared__ __attribute__((aligned(16))) char  smem[65536];       // Ahi|Alo
    __shared__ __attribute__((aligned(16))) float red2[2 * 7 * 288]; // 16128 B
    bf16x8_a* AhiV = (bf16x8_a*)smem;             // vec idx = (kt*4+mt)*64 + lane
    bf16x8_a* AloV = (bf16x8_a*)(smem + 32768);
    f32_a*    zb   = (f32_a*)smem;                // per-wave zbuf view

    const int t    = threadIdx.x;
    const int s0   = blockIdx.x * MSAMP;
    const int wv   = t >> 6, lane = t & 63;
    const int q    = lane >> 4, c = lane & 15;    // C-frag coords
    const int jgl  = lane >> 3, m = lane & 7;     // pass-1 coupling task
    const int jg   = wv * 8 + jgl;                // unit group 0..31
    const int kt0  = jg >> 2, lq0 = jg & 3;
    const int jg2  = wv * 8 + lane;               // pass-2 task (lane<8)
    const int kt2  = jg2 >> 2, lq2 = jg2 & 3;
    const bf16x8 zvec = {};

    float lbv[3], cv[3];
    #pragma unroll
    for (int k = 0; k < 3; ++k) { lbv[k] = lb[k]; cv[k] = 2.0f / (ub[k] - lbv[k]); }

    // ---------------- layer 0: inputs -> first hidden states (A frags) ----------------
    #pragma unroll
    for (int pass = 0; pass < 2; ++pass) {
        if (pass == 1 && t >= 32) continue;
        const int jg0 = pass ? t : (t >> 3);
        const int m0  = pass ? 8 : (t & 7);
        const int n = s0 + m0;
        float x0 = 0.f, x1 = 0.f, x2 = 0.f;
        if (n < N) { x0 = X[n*3+0]; x1 = X[n*3+1]; x2 = X[n*3+2]; }
        const float h0 = cv[0]*(x0 - lbv[0]) - 1.0f;
        const float h1 = cv[1]*(x1 - lbv[1]) - 1.0f;
        const float h2 = cv[2]*(x2 - lbv[2]) - 1.0f;

        float w0v[8], w1v[8], w2v[8], bv[8];
        *(f32x4*)&w0v[0] = *(const f32x4*)&W0[0*256 + jg0*8];
        *(f32x4*)&w0v[4] = *(const f32x4*)&W0[0*256 + jg0*8 + 4];
        *(f32x4*)&w1v[0] = *(const f32x4*)&W0[1*256 + jg0*8];
        *(f32x4*)&w1v[4] = *(const f32x4*)&W0[1*256 + jg0*8 + 4];
        *(f32x4*)&w2v[0] = *(const f32x4*)&W0[2*256 + jg0*8];
        *(f32x4*)&w2v[4] = *(const f32x4*)&W0[2*256 + jg0*8 + 4];
        *(f32x4*)&bv[0]  = *(const f32x4*)&b0[jg0*8];
        *(f32x4*)&bv[4]  = *(const f32x4*)&b0[jg0*8 + 4];

        float st[7][8];
        #pragma unroll
        for (int jj = 0; jj < 8; ++jj) {
            const float zH  = h0*w0v[jj] + h1*w1v[jj] + h2*w2v[jj] + bv[jj];
            const float zt0 = cv[0]*w0v[jj];
            const float zt1 = cv[1]*w1v[jj];
            const float zt2 = cv[2]*w2v[jj];
            const float h   = tanh_fast(zH);
            const float dd  = 1.0f - h*h;
            const float qq  = -2.0f * h * (zt0 + zt1 + zt2);
            st[0][jj] = h;
            st[1][jj] = dd * zt0; st[2][jj] = dd * zt1; st[3][jj] = dd * zt2;
            st[4][jj] = dd * (qq*zt0); st[5][jj] = dd * (qq*zt1); st[6][jj] = dd * (qq*zt2);
        }
        writeA(AhiV, AloV, st, jg0 >> 2, jg0 & 3, m0);
    }
    // zero pad row 63 everywhere: 32 hi + 32 lo vectors
    if (t < 64) {
        const int vid = (((t & 31) >> 2)*4 + 3)*64 + (t & 3)*16 + 15;
        if (t < 32) AhiV[vid] = zvec; else AloV[vid] = zvec;
    }
    __syncthreads();

    // ---------------- hidden layers: GEMM (MFMA) + wave-local coupling ----------------
    #pragma unroll 1
    for (int l = 0; l < 3; ++l) {
        const __bf16* __restrict__ Wb = wsw + (size_t)l * 131072;

        f32x4 acc[4][4];   // [mt][ntl]
        #pragma unroll
        for (int a = 0; a < 4; ++a)
            #pragma unroll
            for (int b = 0; b < 4; ++b) acc[a][b] = (f32x4){0.f, 0.f, 0.f, 0.f};

        #pragma unroll
        for (int kt = 0; kt < 8; ++kt) {
            bf16x8 ah[4], al[4];
            #pragma unroll
            for (int mt = 0; mt < 4; ++mt) {
                const int vid = (kt*4 + mt)*64 + lane;
                ah[mt] = AhiV[vid];
                al[mt] = AloV[vid];
            }
            #pragma unroll
            for (int ntl = 0; ntl < 4; ++ntl) {
                const int nt = wv*4 + ntl;
                const bf16x8 bh = *(const bf16x8*)&Wb[(size_t)((kt*16 + nt)*2 + 0)*512 + lane*8];
                const bf16x8 bl_= *(const bf16x8*)&Wb[(size_t)((kt*16 + nt)*2 + 1)*512 + lane*8];
                #pragma unroll
                for (int mt = 0; mt < 4; ++mt) {
                    f32x4 cc2 = acc[mt][ntl];
                    cc2 = __builtin_amdgcn_mfma_f32_16x16x32_bf16(al[mt], bh,  cc2, 0, 0, 0);
                    cc2 = __builtin_amdgcn_mfma_f32_16x16x32_bf16(ah[mt], bl_, cc2, 0, 0, 0);
                    cc2 = __builtin_amdgcn_mfma_f32_16x16x32_bf16(ah[mt], bh,  cc2, 0, 0, 0);
                    acc[mt][ntl] = cc2;
                }
            }
        }
        __syncthreads();   // b1: all waves' A-frag reads complete; zbuf may clobber own slices

        // C frags -> wave-local zbuf. row=mt*16+q*4+reg, cw=ntl*16+c
        #pragma unroll
        for (int mt = 0; mt < 4; ++mt) {
            #pragma unroll
            for (int reg = 0; reg < 4; ++reg) {
                const int row  = mt*16 + q*4 + reg;
                const int mask = (((row>>2)&3)<<3) | (((row>>4)&1)<<2);
                const int base = wv*2048 + (row>>5)*8192 + (row&31)*64;
                #pragma unroll
                for (int ntl = 0; ntl < 4; ++ntl)
                    zb[base + ((ntl*16 + c) ^ mask)] = acc[mt][ntl][reg];
            }
        }
        asm volatile("s_waitcnt lgkmcnt(0)" ::: "memory");   // C-stores visible to own wave

        // -------- coupling: ALL z-reads first (pass1 + pass2), then computes+writes --------
        float z1[7][8], z2[7][8];
        #pragma unroll
        for (int s = 0; s < 7; ++s) {
            const int row  = s*9 + m;
            const int mask = (((row>>2)&3)<<3) | (((row>>4)&1)<<2);
            const int base = wv*2048 + (row>>5)*8192 + (row&31)*64;
            *(f32x4*)&z1[s][0] = (f32x4)(*(const f32x4_a*)&zb[base + ((jgl*8)     ^ mask)]);
            *(f32x4*)&z1[s][4] = (f32x4)(*(const f32x4_a*)&zb[base + ((jgl*8 + 4) ^ mask)]);
        }
        if (lane < 8) {
            #pragma unroll
            for (int s = 0; s < 7; ++s) {
                const int row  = s*9 + 8;
                const int mask = (((row>>2)&3)<<3) | (((row>>4)&1)<<2);
                const int base = wv*2048 + (row>>5)*8192 + (row&31)*64;
                *(f32x4*)&z2[s][0] = (f32x4)(*(const f32x4_a*)&zb[base + ((lane*8)     ^ mask)]);
                *(f32x4*)&z2[s][4] = (f32x4)(*(const f32x4_a*)&zb[base + ((lane*8 + 4) ^ mask)]);
            }
        }
        asm volatile("s_waitcnt lgkmcnt(0)" ::: "memory");   // all reads in regs before any write

        const float* __restrict__ bb = (l == 0) ? b1 : (l == 1) ? b2 : b3;
        {   // pass 1 (all lanes): task (jg, m)
            float bvv[8];
            *(f32x4*)&bvv[0] = *(const f32x4*)&bb[jg*8];
            *(f32x4*)&bvv[4] = *(const f32x4*)&bb[jg*8 + 4];
            float stt[7][8];
            couple8(z1, bvv, stt);
            if (l < 2) {
                writeA(AhiV, AloV, stt, kt0, lq0, m);
            } else {
                float w4r[16];
                #pragma unroll
                for (int q4 = 0; q4 < 4; ++q4)
                    *(f32x4*)&w4r[q4*4] = *(const f32x4*)&W4[jg*16 + q4*4];
                #pragma unroll
                for (int s = 0; s < 7; ++s) {
                    float p0 = 0.f, p1 = 0.f;
                    #pragma unroll
                    for (int jj = 0; jj < 8; ++jj) {
                        p0 += stt[s][jj] * w4r[jj*2 + 0];
                        p1 += stt[s][jj] * w4r[jj*2 + 1];
                    }
                    red2[(0*7 + s)*288 + jg*9 + m] = p0;
                    red2[(1*7 + s)*288 + jg*9 + m] = p1;
                }
            }
        }
        if (lane < 8) {   // pass 2: task (jg2, m=8)
            float bvv2[8];
            *(f32x4*)&bvv2[0] = *(const f32x4*)&bb[jg2*8];
            *(f32x4*)&bvv2[4] = *(const f32x4*)&bb[jg2*8 + 4];
            float stt2[7][8];
            couple8(z2, bvv2, stt2);
            if (l < 2) {
                writeA(AhiV, AloV, stt2, kt2, lq2, 8);
            } else {
                float w4r2[16];
                #pragma unroll
                for (int q4 = 0; q4 < 4; ++q4)
                    *(f32x4*)&w4r2[q4*4] = *(const f32x4*)&W4[jg2*16 + q4*4];
                #pragma unroll
                for (int s = 0; s < 7; ++s) {
                    float p0 = 0.f, p1 = 0.f;
                    #pragma unroll
                    for (int jj = 0; jj < 8; ++jj) {
                        p0 += stt2[s][jj] * w4r2[jj*2 + 0];
                        p1 += stt2[s][jj] * w4r2[jj*2 + 1];
                    }
                    red2[(0*7 + s)*288 + jg2*9 + 8] = p0;
                    red2[(1*7 + s)*288 + jg2*9 + 8] = p1;
                }
            }
        }
        if (l < 2) {
            // re-zero pad row 63 in wave's own kt slices (zbuf clobbered it);
            // safe: all zbuf reads are already in registers
            if (lane < 16) {
                const int u = (lane >> 2) & 1;
                const int vid = ((2*wv + u)*4 + 3)*64 + (lane & 3)*16 + 15;
                if (lane < 8) AhiV[vid] = zvec; else AloV[vid] = zvec;
            }
        }
        __syncthreads();   // b2: A-frags (l<2) / red2 (l==2) ready
    }

    // ---------------- output reduction (2 ch x 7 states x 9 samples = 126 tasks) ----------------
    if (t < 126) {
        const int i = t & 1, r = t >> 1;   // r = s*9 + mm, 0..62
        const int s = r / 9, mm = r % 9;
        const float* base = &red2[(i*7 + s)*288 + mm];
        float v = 0.f;
        #pragma unroll
        for (int g = 0; g < 32; ++g) v += base[g*9];
        const int n = s0 + mm;
        if (n < N) {
            const size_t N2 = (size_t)N * 2, N3 = (size_t)N * 3;
            if (s == 0)      out[(size_t)n*2 + i] = v + b4[i];
            else if (s <= 3) out[N2 + (size_t)i*N3 + (size_t)n*3 + (s-1)] = v;
            else             out[N2 + 2*N3 + (size_t)i*N3 + (size_t)n*3 + (s-4)] = v;
        }
    }
}

extern "C" void kernel_launch(void* const* d_in, const int* in_sizes, int n_in,
                              void* d_out, int out_size, void* d_ws, size_t ws_size,
                              hipStream_t stream) {
    const float* X  = (const float*)d_in[0];
    const float* W0 = (const float*)d_in[1];
    const float* b0 = (const float*)d_in[2];
    const float* W1 = (const float*)d_in[3];
    const float* b1 = (const float*)d_in[4];
    const float* W2 = (const float*)d_in[5];
    const float* b2 = (const float*)d_in[6];
    const float* W3 = (const float*)d_in[7];
    const float* b3 = (const float*)d_in[8];
    const float* W4 = (const float*)d_in[9];
    const float* b4 = (const float*)d_in[10];
    const float* lb = (const float*)d_in[11];
    const float* ub = (const float*)d_in[12];
    float* out = (float*)d_out;
    __bf16* wsw = (__bf16*)d_ws;   // needs 768 KB

    const int N = in_sizes[0] / 3;

    prep_w<<<768, 256, 0, stream>>>(W1, W2, W3, wsw);

    const int grid = (N + MSAMP - 1) / MSAMP;
    pinn_mfma<<<grid, 256, 0, stream>>>(X, W0, b0, b1, b2, b3, W4, b4, lb, ub,
                                        wsw, out, N);
}

// Round 8
// 335.623 us; speedup vs baseline: 1.0354x; 1.0354x over previous
//
#include <hip/hip_runtime.h>
#include <math.h>

typedef __bf16 bf16x8 __attribute__((ext_vector_type(8)));
typedef float  f32x4  __attribute__((ext_vector_type(4)));
// may_alias views for the unioned LDS region (A-frags <-> per-wave zbuf)
typedef bf16x8 bf16x8_a __attribute__((may_alias));
typedef f32x4  f32x4_a  __attribute__((may_alias));
typedef float  f32_a    __attribute__((may_alias));

#define MSAMP 8       // samples per block; rows: row = s*8 + m, rows 56..63 pad

__device__ __forceinline__ float tanh_fast(float x) {
    // 1 - 2/(exp(2x)+1); v_exp_f32 + v_rcp_f32, ~1e-6 abs error (verified R7: absmax unchanged)
    const float e = __expf(2.0f * x);
    return 1.0f - 2.0f * __builtin_amdgcn_rcpf(e + 1.0f);
}

// W swizzle (bf16 elems): off(l,kt,nt,split,lane,j) =
//   (((l*8+kt)*16+nt)*2+split)*512 + lane*8 + j      ; per-l stride 131072 elems
// One B-fragment (16x16x32): lane holds B[k=kt*32+(lane>>4)*8+j][n=nt*16+(lane&15)]
__global__ void prep_w(const float* __restrict__ W1, const float* __restrict__ W2,
                       const float* __restrict__ W3, __bf16* __restrict__ wsw) {
    const int tid = blockIdx.x * 256 + threadIdx.x;      // 3*8*16*64*8 = 196608
    if (tid >= 3 * 8 * 16 * 64 * 8) return;
    const int j    = tid & 7;
    const int lane = (tid >> 3) & 63;
    const int nt   = (tid >> 9) & 15;
    const int kt   = (tid >> 13) & 7;
    const int l    = tid >> 16;
    const float* W = (l == 0) ? W1 : (l == 1) ? W2 : W3;
    const int k = kt * 32 + (lane >> 4) * 8 + j;
    const int n = nt * 16 + (lane & 15);
    const float w = W[k * 256 + n];
    const __bf16 hi = (__bf16)w;
    const __bf16 lo = (__bf16)(w - (float)hi);
    const size_t base = ((size_t)((l * 8 + kt) * 16 + nt) * 2) * 512 + lane * 8 + j;
    wsw[base]       = hi;
    wsw[base + 512] = lo;
}

// zbuf mapping (wave-local, over the wave's own kt slices {2wv,2wv+1} hi+lo):
//   swblk(row,cb) = cb ^ ((row>>2)&7)    (cb = col>>3, 8-word blocks; f32x4-safe)
//   word(row,cw)  = wv*2048 + (row>>5)*8192 + (row&31)*64 + swblk*8 + (cw&7)
// C-store: bank group = ((ntl*2+(c>>3)) ^ q)&3 -> exactly 2 lanes/bank (free).
__global__ __launch_bounds__(256, 2)
void pinn_mfma(const float* __restrict__ X,
               const float* __restrict__ W0, const float* __restrict__ b0,
               const float* __restrict__ b1, const float* __restrict__ b2,
               const float* __restrict__ b3,
               const float* __restrict__ W4, const float* __restrict__ b4,
               const float* __restrict__ lb, const float* __restrict__ ub,
               const __bf16* __restrict__ wsw,
               float* __restrict__ out, int N)
{
    __shared__ __attribute__((aligned(16))) char  smem[65536];       // Ahi|Alo
    __shared__ __attribute__((aligned(16))) float red2[2 * 7 * 256]; // 14336 B
    bf16x8_a* AhiV = (bf16x8_a*)smem;             // vec idx = (kt*4+mt)*64 + lane
    bf16x8_a* AloV = (bf16x8_a*)(smem + 32768);
    f32_a*    zb   = (f32_a*)smem;                // per-wave zbuf view

    const int t    = threadIdx.x;
    const int s0   = blockIdx.x * MSAMP;
    const int wv   = t >> 6, lane = t & 63;
    const int q    = lane >> 4, c = lane & 15;    // C-frag coords
    const int jgl  = lane >> 3, m = lane & 7;     // coupling task (unit grp, sample)
    const int jg   = wv * 8 + jgl;                // global unit group 0..31
    const int kt0  = jg >> 2, lq0 = jg & 3;       // A-frag coords for jg

    // prologue pad-zero mapping (all 8 kt, by 256 threads)
    const int vidz0 = ((t >> 5) * 4 + 3) * 64 + ((t >> 3) & 3) * 16 + 8 + (t & 7);
    // per-wave pad-zero mapping (wave's own 2 kt slices, by 64 lanes)
    const int vidzw = (((wv * 2 + (lane >> 5)) * 4 + 3) * 64) + (((lane >> 3) & 3) * 16) + 8 + (lane & 7);
    const bf16x8 zvec = {};

    float lbv[3], cv[3];
    #pragma unroll
    for (int k = 0; k < 3; ++k) { lbv[k] = lb[k]; cv[k] = 2.0f / (ub[k] - lbv[k]); }

    // ---------------- layer 0: inputs -> first hidden states (A frags) ----------------
    {
        const int jg0 = t >> 3, m0 = t & 7;       // prologue task mapping (global)
        const int n = s0 + m0;
        float x0 = 0.f, x1 = 0.f, x2 = 0.f;
        if (n < N) { x0 = X[n*3+0]; x1 = X[n*3+1]; x2 = X[n*3+2]; }
        const float h0 = cv[0]*(x0 - lbv[0]) - 1.0f;
        const float h1 = cv[1]*(x1 - lbv[1]) - 1.0f;
        const float h2 = cv[2]*(x2 - lbv[2]) - 1.0f;

        float w0v[8], w1v[8], w2v[8], bv[8];
        *(f32x4*)&w0v[0] = *(const f32x4*)&W0[0*256 + jg0*8];
        *(f32x4*)&w0v[4] = *(const f32x4*)&W0[0*256 + jg0*8 + 4];
        *(f32x4*)&w1v[0] = *(const f32x4*)&W0[1*256 + jg0*8];
        *(f32x4*)&w1v[4] = *(const f32x4*)&W0[1*256 + jg0*8 + 4];
        *(f32x4*)&w2v[0] = *(const f32x4*)&W0[2*256 + jg0*8];
        *(f32x4*)&w2v[4] = *(const f32x4*)&W0[2*256 + jg0*8 + 4];
        *(f32x4*)&bv[0]  = *(const f32x4*)&b0[jg0*8];
        *(f32x4*)&bv[4]  = *(const f32x4*)&b0[jg0*8 + 4];

        float st[7][8];
        #pragma unroll
        for (int jj = 0; jj < 8; ++jj) {
            const float zH  = h0*w0v[jj] + h1*w1v[jj] + h2*w2v[jj] + bv[jj];
            const float zt0 = cv[0]*w0v[jj];
            const float zt1 = cv[1]*w1v[jj];
            const float zt2 = cv[2]*w2v[jj];
            const float h   = tanh_fast(zH);
            const float dd  = 1.0f - h*h;
            const float qq  = -2.0f * h * (zt0 + zt1 + zt2);
            st[0][jj] = h;
            st[1][jj] = dd * zt0; st[2][jj] = dd * zt1; st[3][jj] = dd * zt2;
            st[4][jj] = dd * (qq*zt0); st[5][jj] = dd * (qq*zt1); st[6][jj] = dd * (qq*zt2);
        }
        const int k0a = jg0 >> 2, l0a = jg0 & 3;
        #pragma unroll
        for (int s = 0; s < 7; ++s) {
            const int row = s*8 + m0;
            const int vid = (k0a*4 + (row>>4))*64 + l0a*16 + (row & 15);
            bf16x8 vh, vl;
            #pragma unroll
            for (int jj = 0; jj < 8; ++jj) {
                vh[jj] = (__bf16)st[s][jj];
                vl[jj] = (__bf16)(st[s][jj] - (float)vh[jj]);
            }
            AhiV[vid] = vh;
            AloV[vid] = vl;
        }
        AhiV[vidz0] = zvec;     // zero pad rows 56..63
        AloV[vidz0] = zvec;
    }
    __syncthreads();

    // ---------------- hidden layers: GEMM (MFMA) + wave-local coupling ----------------
    #pragma unroll 1
    for (int l = 0; l < 3; ++l) {
        const __bf16* __restrict__ Wb = wsw + (size_t)l * 131072;

        f32x4 acc[4][4];   // [mt][ntl]
        #pragma unroll
        for (int a = 0; a < 4; ++a)
            #pragma unroll
            for (int b = 0; b < 4; ++b) acc[a][b] = (f32x4){0.f, 0.f, 0.f, 0.f};

        #pragma unroll
        for (int kt = 0; kt < 8; ++kt) {
            bf16x8 ah[4], al[4];
            #pragma unroll
            for (int mt = 0; mt < 4; ++mt) {
                const int vid = (kt*4 + mt)*64 + lane;
                ah[mt] = AhiV[vid];
                al[mt] = AloV[vid];
            }
            #pragma unroll
            for (int ntl = 0; ntl < 4; ++ntl) {
                const int nt = wv*4 + ntl;
                const bf16x8 bh = *(const bf16x8*)&Wb[(size_t)((kt*16 + nt)*2 + 0)*512 + lane*8];
                const bf16x8 bl_= *(const bf16x8*)&Wb[(size_t)((kt*16 + nt)*2 + 1)*512 + lane*8];
                #pragma unroll
                for (int mt = 0; mt < 4; ++mt) {
                    f32x4 cc2 = acc[mt][ntl];
                    cc2 = __builtin_amdgcn_mfma_f32_16x16x32_bf16(al[mt], bh,  cc2, 0, 0, 0);
                    cc2 = __builtin_amdgcn_mfma_f32_16x16x32_bf16(ah[mt], bl_, cc2, 0, 0, 0);
                    cc2 = __builtin_amdgcn_mfma_f32_16x16x32_bf16(ah[mt], bh,  cc2, 0, 0, 0);
                    acc[mt][ntl] = cc2;
                }
            }
        }
        __syncthreads();   // b1: all waves' A-frag reads complete; zbuf may clobber own slices

        // C frags -> wave-local zbuf. row=mt*16+q*4+reg, cw=ntl*16+c
        #pragma unroll
        for (int mt = 0; mt < 4; ++mt) {
            #pragma unroll
            for (int reg = 0; reg < 4; ++reg) {
                const int row  = mt*16 + q*4 + reg;
                const int rsw  = (row >> 2) & 7;
                const int base = wv*2048 + (row>>5)*8192 + (row&31)*64;
                #pragma unroll
                for (int ntl = 0; ntl < 4; ++ntl) {
                    const int cw = ntl*16 + c;
                    zb[base + (((cw>>3) ^ rsw)<<3) + (cw&7)] = acc[mt][ntl][reg];
                }
            }
        }
        asm volatile("s_waitcnt lgkmcnt(0)" ::: "memory");   // C-stores visible to own wave

        // coupling: lane owns (jg = wv*8+jgl, sample m); reads cols jg*8..+7
        {
            const float* __restrict__ bb = (l == 0) ? b1 : (l == 1) ? b2 : b3;
            float bvv[8];
            *(f32x4*)&bvv[0] = *(const f32x4*)&bb[jg*8];
            *(f32x4*)&bvv[4] = *(const f32x4*)&bb[jg*8 + 4];

            float z[7][8];
            #pragma unroll
            for (int s = 0; s < 7; ++s) {
                const int row  = s*8 + m;
                const int base = wv*2048 + (row>>5)*8192 + (row&31)*64
                               + ((jgl ^ ((row>>2)&7))<<3);
                *(f32x4*)&z[s][0] = (f32x4)(*(const f32x4_a*)&zb[base]);
                *(f32x4*)&z[s][4] = (f32x4)(*(const f32x4_a*)&zb[base + 4]);
            }
            float stt[7][8];
            #pragma unroll
            for (int jj = 0; jj < 8; ++jj) {
                const float zH  = z[0][jj] + bvv[jj];
                const float zt0 = z[1][jj], zt1 = z[2][jj], zt2 = z[3][jj];
                const float zr0 = z[4][jj], zr1 = z[5][jj], zr2 = z[6][jj];
                const float h   = tanh_fast(zH);
                const float dd  = 1.0f - h*h;
                const float qq  = -2.0f * h * (zt0 + zt1 + zt2);
                stt[0][jj] = h;
                stt[1][jj] = dd * zt0; stt[2][jj] = dd * zt1; stt[3][jj] = dd * zt2;
                stt[4][jj] = dd * (zr0 + qq*zt0);
                stt[5][jj] = dd * (zr1 + qq*zt1);
                stt[6][jj] = dd * (zr2 + qq*zt2);
            }

            if (l < 2) {
                // write next-layer A-frags into wave's OWN kt slices (data dep on z
                // reads orders these after the reads)
                #pragma unroll
                for (int s = 0; s < 7; ++s) {
                    const int row = s*8 + m;
                    const int vid = (kt0*4 + (row>>4))*64 + lq0*16 + (row & 15);
                    bf16x8 vh, vl;
                    #pragma unroll
                    for (int jj = 0; jj < 8; ++jj) {
                        vh[jj] = (__bf16)stt[s][jj];
                        vl[jj] = (__bf16)(stt[s][jj] - (float)vh[jj]);
                    }
                    AhiV[vid] = vh;
                    AloV[vid] = vl;
                }
                AhiV[vidzw] = zvec;   // re-zero wave's pad rows 56..63
                AloV[vidzw] = zvec;
                __syncthreads();      // b2: A-frags ready for next GEMM
            } else {
                // fused final layer: contract stt with W4 slice -> red2 partials
                float w4r[16];
                #pragma unroll
                for (int q4 = 0; q4 < 4; ++q4)
                    *(f32x4*)&w4r[q4*4] = *(const f32x4*)&W4[jg*16 + q4*4];
                #pragma unroll
                for (int s = 0; s < 7; ++s) {
                    float p0 = 0.f, p1 = 0.f;
                    #pragma unroll
                    for (int jj = 0; jj < 8; ++jj) {
                        p0 += stt[s][jj] * w4r[jj*2 + 0];
                        p1 += stt[s][jj] * w4r[jj*2 + 1];
                    }
                    red2[(0*7 + s)*256 + jg*8 + m] = p0;
                    red2[(1*7 + s)*256 + jg*8 + m] = p1;
                }
                __syncthreads();      // red2 fully written
            }
        }
    }

    // ---------------- output reduction (2 ch x 7 states x 8 samples = 112 tasks) ----------------
    if (t < 112) {
        const int i = t & 1, r = t >> 1;   // r = s*8 + mm, 0..55
        const int s = r >> 3, mm = r & 7;
        const float* base = &red2[(i*7 + s)*256 + mm];
        float v = 0.f;
        #pragma unroll
        for (int g = 0; g < 32; ++g) v += base[g*8];
        const int n = s0 + mm;
        if (n < N) {
            const size_t N2 = (size_t)N * 2, N3 = (size_t)N * 3;
            if (s == 0)      out[(size_t)n*2 + i] = v + b4[i];
            else if (s <= 3) out[N2 + (size_t)i*N3 + (size_t)n*3 + (s-1)] = v;
            else             out[N2 + 2*N3 + (size_t)i*N3 + (size_t)n*3 + (s-4)] = v;
        }
    }
}

extern "C" void kernel_launch(void* const* d_in, const int* in_sizes, int n_in,
                              void* d_out, int out_size, void* d_ws, size_t ws_size,
                              hipStream_t stream) {
    const float* X  = (const float*)d_in[0];
    const float* W0 = (const float*)d_in[1];
    const float* b0 = (const float*)d_in[2];
    const float* W1 = (const float*)d_in[3];
    const float* b1 = (const float*)d_in[4];
    const float* W2 = (const float*)d_in[5];
    const float* b2 = (const float*)d_in[6];
    const float* W3 = (const float*)d_in[7];
    const float* b3 = (const float*)d_in[8];
    const float* W4 = (const float*)d_in[9];
    const float* b4 = (const float*)d_in[10];
    const float* lb = (const float*)d_in[11];
    const float* ub = (const float*)d_in[12];
    float* out = (float*)d_out;
    __bf16* wsw = (__bf16*)d_ws;   // needs 768 KB

    const int N = in_sizes[0] / 3;

    prep_w<<<768, 256, 0, stream>>>(W1, W2, W3, wsw);

    const int grid = (N + MSAMP - 1) / MSAMP;
    pinn_mfma<<<grid, 256, 0, stream>>>(X, W0, b0, b1, b2, b3, W4, b4, lb, ub,
                                        wsw, out, N);
}

// Round 9
// 323.590 us; speedup vs baseline: 1.0739x; 1.0372x over previous
//
#include <hip/hip_runtime.h>
#include <math.h>

typedef __bf16 bf16x8 __attribute__((ext_vector_type(8)));
typedef float  f32x4  __attribute__((ext_vector_type(4)));
// may_alias views for the unioned LDS region (state-frags <-> per-wave zbuf)
typedef bf16x8 bf16x8_a __attribute__((may_alias));
typedef f32x4  f32x4_a  __attribute__((may_alias));
typedef float  f32_a    __attribute__((may_alias));

#define MSAMP 8       // samples per block; state-rows: r = s*8 + m, r 56..63 pad

__device__ __forceinline__ float tanh_fast(float x) {
    // 1 - 2/(exp(2x)+1); ~1e-6 abs error (verified R7/R8: absmax unchanged)
    const float e = __expf(2.0f * x);
    return 1.0f - 2.0f * __builtin_amdgcn_rcpf(e + 1.0f);
}

// W swizzle (bf16 elems) — UNCHANGED from R2..R8 (A-frag and B-frag lane maps
// share the same index formula): off(l,kt,jt,split,lane,jj) =
//   (((l*8+kt)*16+jt)*2+split)*512 + lane*8 + jj ; per-l stride 131072 elems
// Interpreted now as A-fragments of W^T: lane holds
//   A[j = jt*16 + (lane&15)][k = kt*32 + (lane>>4)*8 + jj] = W[k][j]
__global__ void prep_w(const float* __restrict__ W1, const float* __restrict__ W2,
                       const float* __restrict__ W3, __bf16* __restrict__ wsw) {
    const int tid = blockIdx.x * 256 + threadIdx.x;      // 3*8*16*64*8 = 196608
    if (tid >= 3 * 8 * 16 * 64 * 8) return;
    const int j    = tid & 7;
    const int lane = (tid >> 3) & 63;
    const int nt   = (tid >> 9) & 15;
    const int kt   = (tid >> 13) & 7;
    const int l    = tid >> 16;
    const float* W = (l == 0) ? W1 : (l == 1) ? W2 : W3;
    const int k = kt * 32 + (lane >> 4) * 8 + j;
    const int n = nt * 16 + (lane & 15);
    const float w = W[k * 256 + n];
    const __bf16 hi = (__bf16)w;
    const __bf16 lo = (__bf16)(w - (float)hi);
    const size_t base = ((size_t)((l * 8 + kt) * 16 + nt) * 2) * 512 + lane * 8 + j;
    wsw[base]       = hi;
    wsw[base + 512] = lo;
}

// TRANSPOSED GEMM: D[j][r] = sum_k W^T[j][k] * S^T[k][r]  (A = W^T, B = S^T)
// State B-frags in LDS: Bhi|Blo, vec idx = (kt*4 + rt)*64 + lane; lane holds
//   S^T[k = kt*32+(lane>>4)*8+jj][r = rt*16+(lane&15)].
// Wave wv owns M-tiles jt = wv*4..+3 (units wv*64..+63); its coupled units are
// exactly B-frag k-slices {2wv,2wv+1} -> wave-local zbuf aliases those 16KB.
// zbuf word(r, jl) = wv*2048 + (r>>5)*8192 + (r&31)*64 + ((jl + 4*(r&15)) & 63)
// (rotation-by-4c swizzle: all b128 accesses land 8 words/bank on 32 banks).
__global__ __launch_bounds__(256, 2)
void pinn_mfma(const float* __restrict__ X,
               const float* __restrict__ W0, const float* __restrict__ b0,
               const float* __restrict__ b1, const float* __restrict__ b2,
               const float* __restrict__ b3,
               const float* __restrict__ W4, const float* __restrict__ b4,
               const float* __restrict__ lb, const float* __restrict__ ub,
               const __bf16* __restrict__ wsw,
               float* __restrict__ out, int N)
{
    __shared__ __attribute__((aligned(16))) char  smem[65536];       // Bhi|Blo
    __shared__ __attribute__((aligned(16))) float red2[2 * 7 * 256]; // 14336 B
    bf16x8_a* BhiV = (bf16x8_a*)smem;             // vec idx = (kt*4+rt)*64 + lane
    bf16x8_a* BloV = (bf16x8_a*)(smem + 32768);
    f32_a*    zb   = (f32_a*)smem;                // per-wave zbuf view

    const int t    = threadIdx.x;
    const int s0   = blockIdx.x * MSAMP;
    const int wv   = t >> 6, lane = t & 63;
    const int q    = lane >> 4, c = lane & 15;    // C/D + B-frag coords
    const int jgl  = lane >> 3, m = lane & 7;     // coupling task (unit octet, sample)
    const int jg   = wv * 8 + jgl;                // global unit octet 0..31
    const int kt0  = jg >> 2, lq0 = jg & 3;       // B-frag k coords for jg

    // prologue pad-zero mapping (all 8 kt, by 256 threads): zero r=56..63
    const int vidz0 = ((t >> 5) * 4 + 3) * 64 + ((t >> 3) & 3) * 16 + 8 + (t & 7);
    // per-wave pad-zero mapping (wave's own 2 kt slices, by 64 lanes)
    const int vidzw = (((wv * 2 + (lane >> 5)) * 4 + 3) * 64) + (((lane >> 3) & 3) * 16) + 8 + (lane & 7);
    const bf16x8 zvec = {};

    float lbv[3], cv[3];
    #pragma unroll
    for (int k = 0; k < 3; ++k) { lbv[k] = lb[k]; cv[k] = 2.0f / (ub[k] - lbv[k]); }

    // ---------------- layer 0: inputs -> first hidden states (B frags) ----------------
    {
        const int jg0 = t >> 3, m0 = t & 7;       // prologue task mapping (global)
        const int n = s0 + m0;
        float x0 = 0.f, x1 = 0.f, x2 = 0.f;
        if (n < N) { x0 = X[n*3+0]; x1 = X[n*3+1]; x2 = X[n*3+2]; }
        const float h0 = cv[0]*(x0 - lbv[0]) - 1.0f;
        const float h1 = cv[1]*(x1 - lbv[1]) - 1.0f;
        const float h2 = cv[2]*(x2 - lbv[2]) - 1.0f;

        float w0v[8], w1v[8], w2v[8], bv[8];
        *(f32x4*)&w0v[0] = *(const f32x4*)&W0[0*256 + jg0*8];
        *(f32x4*)&w0v[4] = *(const f32x4*)&W0[0*256 + jg0*8 + 4];
        *(f32x4*)&w1v[0] = *(const f32x4*)&W0[1*256 + jg0*8];
        *(f32x4*)&w1v[4] = *(const f32x4*)&W0[1*256 + jg0*8 + 4];
        *(f32x4*)&w2v[0] = *(const f32x4*)&W0[2*256 + jg0*8];
        *(f32x4*)&w2v[4] = *(const f32x4*)&W0[2*256 + jg0*8 + 4];
        *(f32x4*)&bv[0]  = *(const f32x4*)&b0[jg0*8];
        *(f32x4*)&bv[4]  = *(const f32x4*)&b0[jg0*8 + 4];

        float st[7][8];
        #pragma unroll
        for (int jj = 0; jj < 8; ++jj) {
            const float zH  = h0*w0v[jj] + h1*w1v[jj] + h2*w2v[jj] + bv[jj];
            const float zt0 = cv[0]*w0v[jj];
            const float zt1 = cv[1]*w1v[jj];
            const float zt2 = cv[2]*w2v[jj];
            const float h   = tanh_fast(zH);
            const float dd  = 1.0f - h*h;
            const float qq  = -2.0f * h * (zt0 + zt1 + zt2);
            st[0][jj] = h;
            st[1][jj] = dd * zt0; st[2][jj] = dd * zt1; st[3][jj] = dd * zt2;
            st[4][jj] = dd * (qq*zt0); st[5][jj] = dd * (qq*zt1); st[6][jj] = dd * (qq*zt2);
        }
        const int k0a = jg0 >> 2, l0a = jg0 & 3;
        #pragma unroll
        for (int s = 0; s < 7; ++s) {
            const int r = s*8 + m0;
            const int vid = (k0a*4 + (r>>4))*64 + l0a*16 + (r & 15);
            bf16x8 vh, vl;
            #pragma unroll
            for (int jj = 0; jj < 8; ++jj) {
                vh[jj] = (__bf16)st[s][jj];
                vl[jj] = (__bf16)(st[s][jj] - (float)vh[jj]);
            }
            BhiV[vid] = vh;
            BloV[vid] = vl;
        }
        BhiV[vidz0] = zvec;     // zero pad cols r = 56..63
        BloV[vidz0] = zvec;
    }
    __syncthreads();

    // ---------------- hidden layers: transposed GEMM + wave-local coupling ----------------
    #pragma unroll 1
    for (int l = 0; l < 3; ++l) {
        const __bf16* __restrict__ Wb = wsw + (size_t)l * 131072;

        f32x4 acc[4][4];   // [mtj][rt]
        #pragma unroll
        for (int a = 0; a < 4; ++a)
            #pragma unroll
            for (int b = 0; b < 4; ++b) acc[a][b] = (f32x4){0.f, 0.f, 0.f, 0.f};

        #pragma unroll
        for (int kt = 0; kt < 8; ++kt) {
            bf16x8 sh[4], sl[4];            // state B-frags, shared across mtj
            #pragma unroll
            for (int rt = 0; rt < 4; ++rt) {
                const int vid = (kt*4 + rt)*64 + lane;
                sh[rt] = BhiV[vid];
                sl[rt] = BloV[vid];
            }
            #pragma unroll
            for (int mtj = 0; mtj < 4; ++mtj) {
                const int jt = wv*4 + mtj;
                const bf16x8 wh = *(const bf16x8*)&Wb[(size_t)((kt*16 + jt)*2 + 0)*512 + lane*8];
                const bf16x8 wl = *(const bf16x8*)&Wb[(size_t)((kt*16 + jt)*2 + 1)*512 + lane*8];
                #pragma unroll
                for (int rt = 0; rt < 4; ++rt) {
                    f32x4 cc2 = acc[mtj][rt];
                    cc2 = __builtin_amdgcn_mfma_f32_16x16x32_bf16(wl, sh[rt], cc2, 0, 0, 0);
                    cc2 = __builtin_amdgcn_mfma_f32_16x16x32_bf16(wh, sl[rt], cc2, 0, 0, 0);
                    cc2 = __builtin_amdgcn_mfma_f32_16x16x32_bf16(wh, sh[rt], cc2, 0, 0, 0);
                    acc[mtj][rt] = cc2;
                }
            }
        }
        __syncthreads();   // b1: all waves' B-frag reads complete; zbuf may clobber own slices

        // C frags -> wave-local zbuf, VECTOR stores: D row j = wv*64+mtj*16+q*4+reg,
        // col r = rt*16+c; f32x4 regs = 4 consecutive j.
        #pragma unroll
        for (int mtj = 0; mtj < 4; ++mtj) {
            const int jl = mtj*16 + q*4;
            #pragma unroll
            for (int rt = 0; rt < 4; ++rt) {
                const int r = rt*16 + c;
                const int word = wv*2048 + (r>>5)*8192 + (r&31)*64 + ((jl + 4*(r&15)) & 63);
                *(f32x4_a*)&zb[word] = acc[mtj][rt];
            }
        }
        asm volatile("s_waitcnt lgkmcnt(0)" ::: "memory");   // stores visible to own wave

        // coupling: lane owns (jg = wv*8+jgl, sample m); reads z rows r = s*8+m,
        // unit slice jl = jgl*8 .. +7
        {
            const float* __restrict__ bb = (l == 0) ? b1 : (l == 1) ? b2 : b3;
            float bvv[8];
            *(f32x4*)&bvv[0] = *(const f32x4*)&bb[jg*8];
            *(f32x4*)&bvv[4] = *(const f32x4*)&bb[jg*8 + 4];

            float z[7][8];
            #pragma unroll
            for (int s = 0; s < 7; ++s) {
                const int r    = s*8 + m;
                const int base = wv*2048 + (r>>5)*8192 + (r&31)*64;
                const int rot  = 4*(r & 15);
                *(f32x4*)&z[s][0] = (f32x4)(*(const f32x4_a*)&zb[base + ((jgl*8     + rot) & 63)]);
                *(f32x4*)&z[s][4] = (f32x4)(*(const f32x4_a*)&zb[base + ((jgl*8 + 4 + rot) & 63)]);
            }
            float stt[7][8];
            #pragma unroll
            for (int jj = 0; jj < 8; ++jj) {
                const float zH  = z[0][jj] + bvv[jj];
                const float zt0 = z[1][jj], zt1 = z[2][jj], zt2 = z[3][jj];
                const float zr0 = z[4][jj], zr1 = z[5][jj], zr2 = z[6][jj];
                const float h   = tanh_fast(zH);
                const float dd  = 1.0f - h*h;
                const float qq  = -2.0f * h * (zt0 + zt1 + zt2);
                stt[0][jj] = h;
                stt[1][jj] = dd * zt0; stt[2][jj] = dd * zt1; stt[3][jj] = dd * zt2;
                stt[4][jj] = dd * (zr0 + qq*zt0);
                stt[5][jj] = dd * (zr1 + qq*zt1);
                stt[6][jj] = dd * (zr2 + qq*zt2);
            }

            if (l < 2) {
                // write next-layer B-frags into wave's OWN k slices (register data
                // dep on z-reads orders these after the reads)
                #pragma unroll
                for (int s = 0; s < 7; ++s) {
                    const int r = s*8 + m;
                    const int vid = (kt0*4 + (r>>4))*64 + lq0*16 + (r & 15);
                    bf16x8 vh, vl;
                    #pragma unroll
                    for (int jj = 0; jj < 8; ++jj) {
                        vh[jj] = (__bf16)stt[s][jj];
                        vl[jj] = (__bf16)(stt[s][jj] - (float)vh[jj]);
                    }
                    BhiV[vid] = vh;
                    BloV[vid] = vl;
                }
                BhiV[vidzw] = zvec;   // re-zero wave's pad cols r=56..63
                BloV[vidzw] = zvec;
                __syncthreads();      // b2: B-frags ready for next GEMM
            } else {
                // fused final layer: contract stt with W4 slice -> red2 partials
                float w4r[16];
                #pragma unroll
                for (int q4 = 0; q4 < 4; ++q4)
                    *(f32x4*)&w4r[q4*4] = *(const f32x4*)&W4[jg*16 + q4*4];
                #pragma unroll
                for (int s = 0; s < 7; ++s) {
                    float p0 = 0.f, p1 = 0.f;
                    #pragma unroll
                    for (int jj = 0; jj < 8; ++jj) {
                        p0 += stt[s][jj] * w4r[jj*2 + 0];
                        p1 += stt[s][jj] * w4r[jj*2 + 1];
                    }
                    red2[(0*7 + s)*256 + jg*8 + m] = p0;
                    red2[(1*7 + s)*256 + jg*8 + m] = p1;
                }
                __syncthreads();      // red2 fully written
            }
        }
    }

    // ---------------- output reduction (2 ch x 7 states x 8 samples = 112 tasks) ----------------
    if (t < 112) {
        const int i = t & 1, r = t >> 1;   // r = s*8 + mm, 0..55
        const int s = r >> 3, mm = r & 7;
        const float* base = &red2[(i*7 + s)*256 + mm];
        float v = 0.f;
        #pragma unroll
        for (int g = 0; g < 32; ++g) v += base[g*8];
        const int n = s0 + mm;
        if (n < N) {
            const size_t N2 = (size_t)N * 2, N3 = (size_t)N * 3;
            if (s == 0)      out[(size_t)n*2 + i] = v + b4[i];
            else if (s <= 3) out[N2 + (size_t)i*N3 + (size_t)n*3 + (s-1)] = v;
            else             out[N2 + 2*N3 + (size_t)i*N3 + (size_t)n*3 + (s-4)] = v;
        }
    }
}

extern "C" void kernel_launch(void* const* d_in, const int* in_sizes, int n_in,
                              void* d_out, int out_size, void* d_ws, size_t ws_size,
                              hipStream_t stream) {
    const float* X  = (const float*)d_in[0];
    const float* W0 = (const float*)d_in[1];
    const float* b0 = (const float*)d_in[2];
    const float* W1 = (const float*)d_in[3];
    const float* b1 = (const float*)d_in[4];
    const float* W2 = (const float*)d_in[5];
    const float* b2 = (const float*)d_in[6];
    const float* W3 = (const float*)d_in[7];
    const float* b3 = (const float*)d_in[8];
    const float* W4 = (const float*)d_in[9];
    const float* b4 = (const float*)d_in[10];
    const float* lb = (const float*)d_in[11];
    const float* ub = (const float*)d_in[12];
    float* out = (float*)d_out;
    __bf16* wsw = (__bf16*)d_ws;   // needs 768 KB

    const int N = in_sizes[0] / 3;

    prep_w<<<768, 256, 0, stream>>>(W1, W2, W3, wsw);

    const int grid = (N + MSAMP - 1) / MSAMP;
    pinn_mfma<<<grid, 256, 0, stream>>>(X, W0, b0, b1, b2, b3, W4, b4, lb, ub,
                                        wsw, out, N);
}